// Round 9
// baseline (108.239 us; speedup 1.0000x reference)
//
#include <hip/hip_runtime.h>
#include <math.h>

#define B_    16
#define D_    512
#define T_    4096
#define CBN_  1024
#define CD_   8
#define NTOK_ (B_ * T_)   // 65536

// ws float offsets
#define WS_WIN_T  0         // [512][8]  w_in transposed [i][o]
#define WS_NCB    4096      // [1024][8] NEGATED normalized codebook
#define WS_QT     12288     // [1024][4] {||q||, ||q||^2, cc/2, 0}
#define WS_PCB    16384     // [1024][512] w_out @ cb^T + b_out
#define WS_BPART  540672    // [2048] per-block loss partials

#define OUT_OFF_LOSS 33554432               // commitment[16], then codebook[16]
#define OUT_OFF_IDX  33554464               // indices as float [65536]

// ---------------- k0: all precompute (w_in_t, neg-codebook, qtab, pcb) -------
__global__ __launch_bounds__(256) void k0_prep(const float* __restrict__ v_in,
                                               const float* __restrict__ g_in,
                                               const float* __restrict__ v_out,
                                               const float* __restrict__ g_out,
                                               const float* __restrict__ b_out,
                                               const float* __restrict__ codebook,
                                               float* __restrict__ ws) {
    int bid = blockIdx.x, tid = threadIdx.x;
    if (bid == 0) {
        // w_in_t[i][o] = g_in[o] * v_in[o][i] / ||v_in[o,:]||
        __shared__ float part[8][33];
        __shared__ float rn[8];
        int o = tid >> 5;       // 0..7
        int g = tid & 31;       // 0..31
        float s = 0.f;
        for (int i = g * 16; i < g * 16 + 16; ++i) { float x = v_in[o * 512 + i]; s += x * x; }
        part[o][g] = s;
        __syncthreads();
        if (tid < 8) {
            float t2 = 0.f;
            for (int gg = 0; gg < 32; ++gg) t2 += part[tid][gg];
            rn[tid] = g_in[tid] / sqrtf(t2);
        }
        __syncthreads();
        for (int ii = 0; ii < 2; ++ii) {
            int i = tid * 2 + ii;
#pragma unroll
            for (int oo = 0; oo < 8; ++oo)
                ws[WS_WIN_T + i * 8 + oo] = v_in[oo * 512 + i] * rn[oo];
        }
    } else if (bid <= 4) {
        // negated normalized codebook + {qn, sw, cc/2}
        int e = (bid - 1) * 256 + tid;
        const float* c = codebook + (size_t)e * 8;
        float v[8]; float s = 0.f;
#pragma unroll
        for (int j = 0; j < 8; ++j) { v[j] = c[j]; s += v[j] * v[j]; }
        float qn = sqrtf(s);
        float rn = 1.0f / fmaxf(qn, 1e-12f);
        float cs = 0.f;
        float* o = ws + WS_NCB + (size_t)e * 8;
#pragma unroll
        for (int j = 0; j < 8; ++j) { float cn = v[j] * rn; o[j] = -cn; cs += cn * cn; }
        float* q = ws + WS_QT + (size_t)e * 4;
        q[0] = qn; q[1] = s; q[2] = cs * 0.5f; q[3] = 0.f;
    } else {
        // pcb[e][o] = b_out[o] + sum_j w_out[o][j]*cb[e][j]
        int e = bid - 5;
        const float4* cq = (const float4*)(codebook + (size_t)e * 8);
        float4 q0 = cq[0], q1 = cq[1];
        float2 res; float* rp = &res.x;
#pragma unroll
        for (int ii = 0; ii < 2; ++ii) {
            int o = tid * 2 + ii;
            const float4* vr = (const float4*)(v_out + (size_t)o * 8);
            float4 va = vr[0], vb = vr[1];
            float s = va.x * va.x + va.y * va.y + va.z * va.z + va.w * va.w
                    + vb.x * vb.x + vb.y * vb.y + vb.z * vb.z + vb.w * vb.w;
            float rn = g_out[o] / sqrtf(s);
            float x = b_out[o];
            x = fmaf(va.x * rn, q0.x, x); x = fmaf(va.y * rn, q0.y, x);
            x = fmaf(va.z * rn, q0.z, x); x = fmaf(va.w * rn, q0.w, x);
            x = fmaf(vb.x * rn, q1.x, x); x = fmaf(vb.y * rn, q1.y, x);
            x = fmaf(vb.z * rn, q1.z, x); x = fmaf(vb.w * rn, q1.w, x);
            rp[ii] = x;
        }
        ((float2*)(ws + WS_PCB + (size_t)e * 512))[tid] = res;
    }
}

// ============ main fused kernel ==============================================
// grid 2048 x 256 threads (4 waves). Block = 32 tokens: b = blk>>7,
// tb = (blk&127)*32. ph1: 8-way K-split in_proj (p = tid>>5, rows [p*64,+64),
// lane&31 = token), w_in from LDS, z loads batched 16-deep. ph2: lanes 0-31
// finalize z_e. ph3: wave wv scans entries [wv*256,+256) as 4/lane (regs),
// butterfly per token (unroll 2). ph4: lanes 0-31 merge 4 waves + loss.
// ph5: pcb-gather out (tid>>5 = row octant, tid&31 = token).
__global__ __launch_bounds__(256, 4) void vq_main(const float* __restrict__ z,
                                                  const float* __restrict__ b_in,
                                                  const float* __restrict__ ws,
                                                  float* __restrict__ d_out,
                                                  float* __restrict__ bpart) {
    __shared__ float wlds[512 * 8];      // 16 KB: w_in_t [i][o]
    __shared__ float part[8 * 32 * 9];   // 9.2 KB, stride 9
    __shared__ float enorm[32 * 12];     // 1.5 KB: e[8], a, nrm2, zen, pad
    __shared__ float cand_d[128];
    __shared__ int   cand_i[128];
    __shared__ int   idxl[32];

    int tid = threadIdx.x;
    int wv = tid >> 6;
    int l  = tid & 63;
    int p  = tid >> 5, lt = tid & 31;
    int blk = blockIdx.x;
    int b = blk >> 7;
    int tb = (blk & 127) << 5;

    // ---- stage w_in_t (conflict-free float4 copy) ----
    {
        const float4* wsrc = (const float4*)(ws + WS_WIN_T);
#pragma unroll
        for (int k = 0; k < 4; ++k) ((float4*)wlds)[tid + k * 256] = wsrc[tid + k * 256];
    }
    __syncthreads();

    // ---- ph1: in_proj partial; group p covers rows [p*64,+64), 16-deep z batches ----
    {
        float acc[8];
#pragma unroll
        for (int j = 0; j < 8; ++j) acc[j] = 0.f;
        const float* zp = z + (size_t)b * D_ * T_ + (size_t)(p * 64) * T_ + tb + lt;
        const float4* wp = ((const float4*)wlds) + p * 128;
        for (int ib = 0; ib < 4; ++ib) {
            float vz[16];
#pragma unroll
            for (int u = 0; u < 16; ++u) vz[u] = zp[(size_t)(ib * 16 + u) * T_];
#pragma unroll
            for (int u = 0; u < 16; ++u) {
                int i = ib * 16 + u;
                float4 wa = wp[i * 2];
                float4 wb = wp[i * 2 + 1];
                acc[0] = fmaf(wa.x, vz[u], acc[0]); acc[1] = fmaf(wa.y, vz[u], acc[1]);
                acc[2] = fmaf(wa.z, vz[u], acc[2]); acc[3] = fmaf(wa.w, vz[u], acc[3]);
                acc[4] = fmaf(wb.x, vz[u], acc[4]); acc[5] = fmaf(wb.y, vz[u], acc[5]);
                acc[6] = fmaf(wb.z, vz[u], acc[6]); acc[7] = fmaf(wb.w, vz[u], acc[7]);
            }
        }
        float* pp = &part[(p * 32 + lt) * 9];
#pragma unroll
        for (int j = 0; j < 8; ++j) pp[j] = acc[j];
    }
    __syncthreads();

    // ---- ph2: lanes 0-31 finalize z_e (bias + 8 partials ascending) ----
    if (tid < 32) {
        float ze[8];
#pragma unroll
        for (int j = 0; j < 8; ++j) ze[j] = b_in[j];
#pragma unroll
        for (int pp = 0; pp < 8; ++pp)
#pragma unroll
            for (int j = 0; j < 8; ++j) ze[j] += part[(pp * 32 + tid) * 9 + j];
        float nrm2 = ze[0] * ze[0] + ze[1] * ze[1] + ze[2] * ze[2] + ze[3] * ze[3]
                   + ze[4] * ze[4] + ze[5] * ze[5] + ze[6] * ze[6] + ze[7] * ze[7];
        float zen = fmaxf(sqrtf(nrm2), 1e-12f);
        float r = 1.0f / zen;
        float e0 = ze[0] * r, e1 = ze[1] * r, e2 = ze[2] * r, e3 = ze[3] * r;
        float e4 = ze[4] * r, e5 = ze[5] * r, e6 = ze[6] * r, e7 = ze[7] * r;
        float a = e0 * e0 + e1 * e1 + e2 * e2 + e3 * e3
                + e4 * e4 + e5 * e5 + e6 * e6 + e7 * e7;
        float* ep = &enorm[tid * 12];
        ep[0] = e0; ep[1] = e1; ep[2] = e2; ep[3] = e3;
        ep[4] = e4; ep[5] = e5; ep[6] = e6; ep[7] = e7;
        ep[8] = a; ep[9] = nrm2; ep[10] = zen; ep[11] = 0.f;
    }

    // ---- load 4 neg-codebook entries/lane: e = wv*256 + k*64 + l ----
    float nc[4][8]; float c2[4];
    int ebase = wv * 256;
#pragma unroll
    for (int k = 0; k < 4; ++k) {
        int e = ebase + k * 64 + l;
        const float4* cp = (const float4*)(ws + WS_NCB + (size_t)e * 8);
        float4 p0 = cp[0], p1 = cp[1];
        nc[k][0] = p0.x; nc[k][1] = p0.y; nc[k][2] = p0.z; nc[k][3] = p0.w;
        nc[k][4] = p1.x; nc[k][5] = p1.y; nc[k][6] = p1.z; nc[k][7] = p1.w;
        c2[k] = ws[WS_QT + (size_t)e * 4 + 2];
    }
    __syncthreads();

    // ---- ph3: score = cc/2 - dot; per-token butterfly lex-min (unroll 2) ----
#pragma unroll 2
    for (int s = 0; s < 32; ++s) {
        float4 E0 = ((float4*)enorm)[s * 3 + 0];
        float4 E1 = ((float4*)enorm)[s * 3 + 1];
        float sb = 3.4e38f; int bi = 0x7fffffff;
#pragma unroll
        for (int k = 0; k < 4; ++k) {
            float sc = fmaf(nc[k][0], E0.x, c2[k]);
            sc = fmaf(nc[k][1], E0.y, sc);
            sc = fmaf(nc[k][2], E0.z, sc);
            sc = fmaf(nc[k][3], E0.w, sc);
            sc = fmaf(nc[k][4], E1.x, sc);
            sc = fmaf(nc[k][5], E1.y, sc);
            sc = fmaf(nc[k][6], E1.z, sc);
            sc = fmaf(nc[k][7], E1.w, sc);
            int e = ebase + k * 64 + l;
            if (sc < sb) { sb = sc; bi = e; }   // strict < -> first-min
        }
#pragma unroll
        for (int off = 1; off < 64; off <<= 1) {
            float ov = __shfl_xor(sb, off, 64);
            int   oi = __shfl_xor(bi, off, 64);
            if (ov < sb || (ov == sb && oi < bi)) { sb = ov; bi = oi; }
        }
        if (l == 0) { cand_d[wv * 32 + s] = sb; cand_i[wv * 32 + s] = bi; }
    }
    __syncthreads();

    // ---- ph4: lanes 0-31 merge 4 waves + loss, one parallel pass ----
    if (tid < 32) {
        float d0 = cand_d[tid]; int i0 = cand_i[tid];
#pragma unroll
        for (int w = 1; w < 4; ++w) {
            float dw = cand_d[w * 32 + tid];
            if (dw < d0) { d0 = dw; i0 = cand_i[w * 32 + tid]; }  // slices ascending
        }
        idxl[tid] = i0;
        int tok = blk * 32 + tid;
        d_out[OUT_OFF_IDX + tok] = (float)i0;
        float nrm2 = enorm[tid * 12 + 9], zen = enorm[tid * 12 + 10];
        float4 qt = ((const float4*)(ws + WS_QT))[i0];   // {qn, sw, cc2, 0}
        float dot = qt.z - d0;
        float lv = nrm2 - 2.0f * dot * zen * qt.x + qt.y;
#pragma unroll
        for (int off = 1; off < 32; off <<= 1) lv += __shfl_xor(lv, off, 64);
        if (tid == 0) bpart[blk] = lv;
    }
    __syncthreads();

    // ---- ph5: pcb-gather out; p = row octant [p*64,+64), lt = token ----
    {
        int idx = idxl[lt];
        const float4* pr = (const float4*)(ws + WS_PCB + (size_t)idx * 512 + p * 64);
        float* op = d_out + (size_t)b * D_ * T_ + (size_t)(p * 64) * T_ + tb + lt;
#pragma unroll 8
        for (int k = 0; k < 16; ++k) {
            float4 v = pr[k];
            op[(size_t)(k * 4 + 0) * T_] = v.x;
            op[(size_t)(k * 4 + 1) * T_] = v.y;
            op[(size_t)(k * 4 + 2) * T_] = v.z;
            op[(size_t)(k * 4 + 3) * T_] = v.w;
        }
    }
}

// ============ finalize: per-batch loss reduction =============================
__global__ __launch_bounds__(64) void vq_finalize(const float* __restrict__ bpart,
                                                  float* __restrict__ d_out) {
    int tid = threadIdx.x;
    if (tid < B_) {
        float s = 0.f;
        for (int k = 0; k < 128; ++k) s += bpart[tid * 128 + k];
        float m = s * (1.0f / (CD_ * T_));
        d_out[OUT_OFF_LOSS + tid] = m;
        d_out[OUT_OFF_LOSS + 16 + tid] = m;
    }
}

// ---------------- launch -----------------------------------------------------
extern "C" void kernel_launch(void* const* d_in, const int* in_sizes, int n_in,
                              void* d_out, int out_size, void* d_ws, size_t ws_size,
                              hipStream_t stream) {
    (void)in_sizes; (void)n_in; (void)out_size; (void)ws_size;
    const float* z        = (const float*)d_in[0];
    const float* v_in     = (const float*)d_in[1];
    const float* g_in     = (const float*)d_in[2];
    const float* b_in     = (const float*)d_in[3];
    const float* v_out    = (const float*)d_in[4];
    const float* g_out    = (const float*)d_in[5];
    const float* b_out    = (const float*)d_in[6];
    const float* codebook = (const float*)d_in[7];
    float* ws  = (float*)d_ws;
    float* out = (float*)d_out;

    hipLaunchKernelGGL(k0_prep, dim3(5 + CBN_), dim3(256), 0, stream,
                       v_in, g_in, v_out, g_out, b_out, codebook, ws);
    hipLaunchKernelGGL(vq_main, dim3(NTOK_ / 32), dim3(256), 0, stream,
                       z, b_in, ws, out, ws + WS_BPART);
    hipLaunchKernelGGL(vq_finalize, dim3(1), dim3(64), 0, stream,
                       ws + WS_BPART, out);
}

// Round 10
// 108.147 us; speedup vs baseline: 1.0008x; 1.0008x over previous
//
#include <hip/hip_runtime.h>
#include <math.h>

#define B_    16
#define D_    512
#define T_    4096
#define CBN_  1024
#define CD_   8
#define NTOK_ (B_ * T_)   // 65536

// ws float offsets
#define WS_WIN_T  0         // [512][8]  w_in transposed [i][o]
#define WS_NCB    4096      // [1024][8] NEGATED normalized codebook
#define WS_QT     12288     // [1024][4] {||q||, ||q||^2, cc/2, 0}
#define WS_PCB    16384     // [1024][512] w_out @ cb^T + b_out
#define WS_BPART  540672    // [4096] per-block loss partials

#define OUT_OFF_LOSS 33554432               // commitment[16], then codebook[16]
#define OUT_OFF_IDX  33554464               // indices as float [65536]

// ---------------- k0: all precompute (w_in_t, neg-codebook, qtab, pcb) -------
__global__ __launch_bounds__(256) void k0_prep(const float* __restrict__ v_in,
                                               const float* __restrict__ g_in,
                                               const float* __restrict__ v_out,
                                               const float* __restrict__ g_out,
                                               const float* __restrict__ b_out,
                                               const float* __restrict__ codebook,
                                               float* __restrict__ ws) {
    int bid = blockIdx.x, tid = threadIdx.x;
    if (bid == 0) {
        // w_in_t[i][o] = g_in[o] * v_in[o][i] / ||v_in[o,:]||
        __shared__ float part[8][33];
        __shared__ float rn[8];
        int o = tid >> 5;       // 0..7
        int g = tid & 31;       // 0..31
        float s = 0.f;
        for (int i = g * 16; i < g * 16 + 16; ++i) { float x = v_in[o * 512 + i]; s += x * x; }
        part[o][g] = s;
        __syncthreads();
        if (tid < 8) {
            float t2 = 0.f;
            for (int gg = 0; gg < 32; ++gg) t2 += part[tid][gg];
            rn[tid] = g_in[tid] / sqrtf(t2);
        }
        __syncthreads();
        for (int ii = 0; ii < 2; ++ii) {
            int i = tid * 2 + ii;
#pragma unroll
            for (int oo = 0; oo < 8; ++oo)
                ws[WS_WIN_T + i * 8 + oo] = v_in[oo * 512 + i] * rn[oo];
        }
    } else if (bid <= 4) {
        // negated normalized codebook + {qn, sw, cc/2}
        int e = (bid - 1) * 256 + tid;
        const float* c = codebook + (size_t)e * 8;
        float v[8]; float s = 0.f;
#pragma unroll
        for (int j = 0; j < 8; ++j) { v[j] = c[j]; s += v[j] * v[j]; }
        float qn = sqrtf(s);
        float rn = 1.0f / fmaxf(qn, 1e-12f);
        float cs = 0.f;
        float* o = ws + WS_NCB + (size_t)e * 8;
#pragma unroll
        for (int j = 0; j < 8; ++j) { float cn = v[j] * rn; o[j] = -cn; cs += cn * cn; }
        float* q = ws + WS_QT + (size_t)e * 4;
        q[0] = qn; q[1] = s; q[2] = cs * 0.5f; q[3] = 0.f;
    } else {
        // pcb[e][o] = b_out[o] + sum_j w_out[o][j]*cb[e][j]
        int e = bid - 5;
        const float4* cq = (const float4*)(codebook + (size_t)e * 8);
        float4 q0 = cq[0], q1 = cq[1];
        float2 res; float* rp = &res.x;
#pragma unroll
        for (int ii = 0; ii < 2; ++ii) {
            int o = tid * 2 + ii;
            const float4* vr = (const float4*)(v_out + (size_t)o * 8);
            float4 va = vr[0], vb = vr[1];
            float s = va.x * va.x + va.y * va.y + va.z * va.z + va.w * va.w
                    + vb.x * vb.x + vb.y * vb.y + vb.z * vb.z + vb.w * vb.w;
            float rn = g_out[o] / sqrtf(s);
            float x = b_out[o];
            x = fmaf(va.x * rn, q0.x, x); x = fmaf(va.y * rn, q0.y, x);
            x = fmaf(va.z * rn, q0.z, x); x = fmaf(va.w * rn, q0.w, x);
            x = fmaf(vb.x * rn, q1.x, x); x = fmaf(vb.y * rn, q1.y, x);
            x = fmaf(vb.z * rn, q1.z, x); x = fmaf(vb.w * rn, q1.w, x);
            rp[ii] = x;
        }
        ((float2*)(ws + WS_PCB + (size_t)e * 512))[tid] = res;
    }
}

// ============ main fused kernel ==============================================
// grid 4096 x 256 threads (4 waves). Block = 16 tokens: b = blk>>8,
// tb = (blk&255)*16. Thread (p = tid>>2 in 0..63, q = tid&3): in_proj over
// rows [8p,8p+8) x 4 tokens (float4 z loads); 16-lane shuffle reduce of
// K-partials within each wave; ph2: threads 0-15 finalize z_e. ph3: wave wv
// scans codebook slice [wv*256,+256) as 4 entries/lane (regs), butterfly per
// token. ph4: threads 0-15 merge + loss. ph5: pcb-gather with float4 stores.
__global__ __launch_bounds__(256, 3) void vq_main(const float* __restrict__ z,
                                                  const float* __restrict__ b_in,
                                                  const float* __restrict__ ws,
                                                  float* __restrict__ d_out,
                                                  float* __restrict__ bpart) {
    __shared__ float part[4 * 16 * 8];   // [wv][t_local][j], 2 KB
    __shared__ float enorm[16 * 12];     // e[8], a, nrm2, zen, pad
    __shared__ float cand_d[64];         // [wv][token]
    __shared__ int   cand_i[64];
    __shared__ int   idxl[16];

    int tid = threadIdx.x;
    int wv = tid >> 6;
    int l  = tid & 63;
    int p  = tid >> 2;       // 0..63 K-group: rows [8p, 8p+8)
    int q  = tid & 3;        // token quad: tokens tb + 4q + ti
    int blk = blockIdx.x;
    int b  = blk >> 8;
    int tb = (blk & 255) << 4;

    // ---- ph1: in_proj; 16 w-loads (L1-hot) + 8 float4 z-loads + 256 FMA ----
    float acc[4][8];
#pragma unroll
    for (int ti = 0; ti < 4; ++ti)
#pragma unroll
        for (int j = 0; j < 8; ++j) acc[ti][j] = 0.f;
    {
        const float4* wsrc = ((const float4*)(ws + WS_WIN_T)) + p * 16;
        const float* zp = z + (size_t)b * D_ * T_ + (size_t)(8 * p) * T_ + tb + 4 * q;
        float4 zv[8];
#pragma unroll
        for (int i = 0; i < 8; ++i) zv[i] = *(const float4*)(zp + (size_t)i * T_);
#pragma unroll
        for (int i = 0; i < 8; ++i) {
            float4 wa = wsrc[i * 2];
            float4 wb = wsrc[i * 2 + 1];
            float vv[4] = {zv[i].x, zv[i].y, zv[i].z, zv[i].w};
#pragma unroll
            for (int ti = 0; ti < 4; ++ti) {
                acc[ti][0] = fmaf(wa.x, vv[ti], acc[ti][0]);
                acc[ti][1] = fmaf(wa.y, vv[ti], acc[ti][1]);
                acc[ti][2] = fmaf(wa.z, vv[ti], acc[ti][2]);
                acc[ti][3] = fmaf(wa.w, vv[ti], acc[ti][3]);
                acc[ti][4] = fmaf(wb.x, vv[ti], acc[ti][4]);
                acc[ti][5] = fmaf(wb.y, vv[ti], acc[ti][5]);
                acc[ti][6] = fmaf(wb.z, vv[ti], acc[ti][6]);
                acc[ti][7] = fmaf(wb.w, vv[ti], acc[ti][7]);
            }
        }
    }
    // 16-lane butterfly over K-groups within the wave (lanes stride 4, same q)
#pragma unroll
    for (int off = 4; off < 64; off <<= 1)
#pragma unroll
        for (int ti = 0; ti < 4; ++ti)
#pragma unroll
            for (int j = 0; j < 8; ++j)
                acc[ti][j] += __shfl_xor(acc[ti][j], off, 64);
    if (l < 4) {   // l == q, p'==0: holds wave partial for quad q
#pragma unroll
        for (int ti = 0; ti < 4; ++ti)
#pragma unroll
            for (int j = 0; j < 8; ++j)
                part[wv * 128 + (4 * l + ti) * 8 + j] = acc[ti][j];
    }
    __syncthreads();

    // ---- ph2: threads 0-15 finalize z_e (bias + 4 wave-partials ascending) ----
    if (tid < 16) {
        float ze[8];
#pragma unroll
        for (int j = 0; j < 8; ++j)
            ze[j] = b_in[j] + part[tid * 8 + j] + part[128 + tid * 8 + j]
                  + part[256 + tid * 8 + j] + part[384 + tid * 8 + j];
        float nrm2 = ze[0] * ze[0] + ze[1] * ze[1] + ze[2] * ze[2] + ze[3] * ze[3]
                   + ze[4] * ze[4] + ze[5] * ze[5] + ze[6] * ze[6] + ze[7] * ze[7];
        float zen = fmaxf(sqrtf(nrm2), 1e-12f);
        float r = 1.0f / zen;
        float e0 = ze[0] * r, e1 = ze[1] * r, e2 = ze[2] * r, e3 = ze[3] * r;
        float e4 = ze[4] * r, e5 = ze[5] * r, e6 = ze[6] * r, e7 = ze[7] * r;
        float a = e0 * e0 + e1 * e1 + e2 * e2 + e3 * e3
                + e4 * e4 + e5 * e5 + e6 * e6 + e7 * e7;
        float* ep = &enorm[tid * 12];
        ep[0] = e0; ep[1] = e1; ep[2] = e2; ep[3] = e3;
        ep[4] = e4; ep[5] = e5; ep[6] = e6; ep[7] = e7;
        ep[8] = a; ep[9] = nrm2; ep[10] = zen; ep[11] = 0.f;
    }

    // ---- load 4 neg-codebook entries/lane: e = wv*256 + k*64 + l ----
    float nc[4][8]; float c2[4];
    int ebase = wv * 256;
#pragma unroll
    for (int k = 0; k < 4; ++k) {
        int e = ebase + k * 64 + l;
        const float4* cp = (const float4*)(ws + WS_NCB + (size_t)e * 8);
        float4 p0 = cp[0], p1 = cp[1];
        nc[k][0] = p0.x; nc[k][1] = p0.y; nc[k][2] = p0.z; nc[k][3] = p0.w;
        nc[k][4] = p1.x; nc[k][5] = p1.y; nc[k][6] = p1.z; nc[k][7] = p1.w;
        c2[k] = ws[WS_QT + (size_t)e * 4 + 2];
    }
    __syncthreads();

    // ---- ph3: score = cc/2 - dot; per-token 64-lane lex-min butterfly ----
#pragma unroll 2
    for (int s = 0; s < 16; ++s) {
        float4 E0 = ((float4*)enorm)[s * 3 + 0];
        float4 E1 = ((float4*)enorm)[s * 3 + 1];
        float sb = 3.4e38f; int bi = 0x7fffffff;
#pragma unroll
        for (int k = 0; k < 4; ++k) {
            float sc = fmaf(nc[k][0], E0.x, c2[k]);
            sc = fmaf(nc[k][1], E0.y, sc);
            sc = fmaf(nc[k][2], E0.z, sc);
            sc = fmaf(nc[k][3], E0.w, sc);
            sc = fmaf(nc[k][4], E1.x, sc);
            sc = fmaf(nc[k][5], E1.y, sc);
            sc = fmaf(nc[k][6], E1.z, sc);
            sc = fmaf(nc[k][7], E1.w, sc);
            int e = ebase + k * 64 + l;
            if (sc < sb) { sb = sc; bi = e; }   // strict < -> first-min
        }
#pragma unroll
        for (int off = 1; off < 64; off <<= 1) {
            float ov = __shfl_xor(sb, off, 64);
            int   oi = __shfl_xor(bi, off, 64);
            if (ov < sb || (ov == sb && oi < bi)) { sb = ov; bi = oi; }
        }
        if (l == 0) { cand_d[wv * 16 + s] = sb; cand_i[wv * 16 + s] = bi; }
    }
    __syncthreads();

    // ---- ph4: threads 0-15 merge 4 wave-slices + loss ----
    if (tid < 16) {
        float d0 = cand_d[tid]; int i0 = cand_i[tid];
#pragma unroll
        for (int w = 1; w < 4; ++w) {
            float dw = cand_d[w * 16 + tid];
            if (dw < d0) { d0 = dw; i0 = cand_i[w * 16 + tid]; }  // slices ascending
        }
        idxl[tid] = i0;
        int tok = blk * 16 + tid;
        d_out[OUT_OFF_IDX + tok] = (float)i0;
        float nrm2 = enorm[tid * 12 + 9], zen = enorm[tid * 12 + 10];
        float4 qt = ((const float4*)(ws + WS_QT))[i0];   // {qn, sw, cc2, 0}
        float dot = qt.z - d0;
        float lv = nrm2 - 2.0f * dot * zen * qt.x + qt.y;
#pragma unroll
        for (int off = 1; off < 16; off <<= 1) lv += __shfl_xor(lv, off, 64);
        if (tid == 0) bpart[blk] = lv;
    }
    __syncthreads();

    // ---- ph5: pcb-gather + float4 stores; thread (rg = tid>>2, q2 = tid&3) ----
    {
        int rg = tid >> 2, q2 = tid & 3;
        int i0 = idxl[4 * q2 + 0], i1 = idxl[4 * q2 + 1];
        int i2 = idxl[4 * q2 + 2], i3 = idxl[4 * q2 + 3];
        const float* base = ws + WS_PCB;
        float pa[8], pb[8], pc[8], pd[8];
        *(float4*)&pa[0] = *(const float4*)(base + (size_t)i0 * 512 + 8 * rg);
        *(float4*)&pa[4] = *(const float4*)(base + (size_t)i0 * 512 + 8 * rg + 4);
        *(float4*)&pb[0] = *(const float4*)(base + (size_t)i1 * 512 + 8 * rg);
        *(float4*)&pb[4] = *(const float4*)(base + (size_t)i1 * 512 + 8 * rg + 4);
        *(float4*)&pc[0] = *(const float4*)(base + (size_t)i2 * 512 + 8 * rg);
        *(float4*)&pc[4] = *(const float4*)(base + (size_t)i2 * 512 + 8 * rg + 4);
        *(float4*)&pd[0] = *(const float4*)(base + (size_t)i3 * 512 + 8 * rg);
        *(float4*)&pd[4] = *(const float4*)(base + (size_t)i3 * 512 + 8 * rg + 4);
        float* op = d_out + (size_t)b * D_ * T_ + (size_t)(8 * rg) * T_ + tb + 4 * q2;
#pragma unroll
        for (int r = 0; r < 8; ++r)
            *(float4*)(op + (size_t)r * T_) = make_float4(pa[r], pb[r], pc[r], pd[r]);
    }
}

// ============ finalize: per-batch loss reduction =============================
__global__ __launch_bounds__(256) void vq_finalize(const float* __restrict__ bpart,
                                                   float* __restrict__ d_out) {
    __shared__ float red[16][17];
    int tid = threadIdx.x;
    int bb = tid >> 4, c = tid & 15;
    float s = 0.f;
    for (int k = 0; k < 16; ++k) s += bpart[bb * 256 + c * 16 + k];
    red[bb][c] = s;
    __syncthreads();
    if (tid < 16) {
        float t = 0.f;
        for (int k = 0; k < 16; ++k) t += red[tid][k];
        float m = t * (1.0f / (CD_ * T_));
        d_out[OUT_OFF_LOSS + tid] = m;
        d_out[OUT_OFF_LOSS + 16 + tid] = m;
    }
}

// ---------------- launch -----------------------------------------------------
extern "C" void kernel_launch(void* const* d_in, const int* in_sizes, int n_in,
                              void* d_out, int out_size, void* d_ws, size_t ws_size,
                              hipStream_t stream) {
    (void)in_sizes; (void)n_in; (void)out_size; (void)ws_size;
    const float* z        = (const float*)d_in[0];
    const float* v_in     = (const float*)d_in[1];
    const float* g_in     = (const float*)d_in[2];
    const float* b_in     = (const float*)d_in[3];
    const float* v_out    = (const float*)d_in[4];
    const float* g_out    = (const float*)d_in[5];
    const float* b_out    = (const float*)d_in[6];
    const float* codebook = (const float*)d_in[7];
    float* ws  = (float*)d_ws;
    float* out = (float*)d_out;

    hipLaunchKernelGGL(k0_prep, dim3(5 + CBN_), dim3(256), 0, stream,
                       v_in, g_in, v_out, g_out, b_out, codebook, ws);
    hipLaunchKernelGGL(vq_main, dim3(NTOK_ / 16), dim3(256), 0, stream,
                       z, b_in, ws, out, ws + WS_BPART);
    hipLaunchKernelGGL(vq_finalize, dim3(1), dim3(256), 0, stream,
                       ws + WS_BPART, out);
}

// Round 11
// 89.735 us; speedup vs baseline: 1.2062x; 1.2052x over previous
//
#include <hip/hip_runtime.h>
#include <math.h>

#define B_    16
#define D_    512
#define T_    4096
#define CBN_  1024
#define CD_   8
#define NTOK_ (B_ * T_)   // 65536

// ws float offsets
#define WS_WIN_T  0         // [512][8]  w_in transposed [i][o]
#define WS_NCB    4096      // [1024][8] NEGATED normalized codebook
#define WS_QT     12288     // [1024][4] {||q||, ||q||^2, cc/2, 0}
#define WS_PCB    16384     // [1024][512] w_out @ cb^T + b_out
#define WS_BPART  540672    // [2048] per-block loss partials

#define OUT_OFF_LOSS 33554432               // commitment[16], then codebook[16]
#define OUT_OFF_IDX  33554464               // indices as float [65536]

// ---------------- k0: all precompute (w_in_t, neg-codebook, qtab, pcb) -------
__global__ __launch_bounds__(256) void k0_prep(const float* __restrict__ v_in,
                                               const float* __restrict__ g_in,
                                               const float* __restrict__ v_out,
                                               const float* __restrict__ g_out,
                                               const float* __restrict__ b_out,
                                               const float* __restrict__ codebook,
                                               float* __restrict__ ws) {
    int bid = blockIdx.x, tid = threadIdx.x;
    if (bid == 0) {
        // w_in_t[i][o] = g_in[o] * v_in[o][i] / ||v_in[o,:]||
        __shared__ float part[8][33];
        __shared__ float rn[8];
        int o = tid >> 5;       // 0..7
        int g = tid & 31;       // 0..31
        float s = 0.f;
        for (int i = g * 16; i < g * 16 + 16; ++i) { float x = v_in[o * 512 + i]; s += x * x; }
        part[o][g] = s;
        __syncthreads();
        if (tid < 8) {
            float t2 = 0.f;
            for (int gg = 0; gg < 32; ++gg) t2 += part[tid][gg];
            rn[tid] = g_in[tid] / sqrtf(t2);
        }
        __syncthreads();
        for (int ii = 0; ii < 2; ++ii) {
            int i = tid * 2 + ii;
#pragma unroll
            for (int oo = 0; oo < 8; ++oo)
                ws[WS_WIN_T + i * 8 + oo] = v_in[oo * 512 + i] * rn[oo];
        }
    } else if (bid <= 4) {
        // negated normalized codebook + {qn, sw, cc/2}
        int e = (bid - 1) * 256 + tid;
        const float* c = codebook + (size_t)e * 8;
        float v[8]; float s = 0.f;
#pragma unroll
        for (int j = 0; j < 8; ++j) { v[j] = c[j]; s += v[j] * v[j]; }
        float qn = sqrtf(s);
        float rn = 1.0f / fmaxf(qn, 1e-12f);
        float cs = 0.f;
        float* o = ws + WS_NCB + (size_t)e * 8;
#pragma unroll
        for (int j = 0; j < 8; ++j) { float cn = v[j] * rn; o[j] = -cn; cs += cn * cn; }
        float* q = ws + WS_QT + (size_t)e * 4;
        q[0] = qn; q[1] = s; q[2] = cs * 0.5f; q[3] = 0.f;
    } else {
        // pcb[e][o] = b_out[o] + sum_j w_out[o][j]*cb[e][j]
        int e = bid - 5;
        const float4* cq = (const float4*)(codebook + (size_t)e * 8);
        float4 q0 = cq[0], q1 = cq[1];
        float2 res; float* rp = &res.x;
#pragma unroll
        for (int ii = 0; ii < 2; ++ii) {
            int o = tid * 2 + ii;
            const float4* vr = (const float4*)(v_out + (size_t)o * 8);
            float4 va = vr[0], vb = vr[1];
            float s = va.x * va.x + va.y * va.y + va.z * va.z + va.w * va.w
                    + vb.x * vb.x + vb.y * vb.y + vb.z * vb.z + vb.w * vb.w;
            float rn = g_out[o] / sqrtf(s);
            float x = b_out[o];
            x = fmaf(va.x * rn, q0.x, x); x = fmaf(va.y * rn, q0.y, x);
            x = fmaf(va.z * rn, q0.z, x); x = fmaf(va.w * rn, q0.w, x);
            x = fmaf(vb.x * rn, q1.x, x); x = fmaf(vb.y * rn, q1.y, x);
            x = fmaf(vb.z * rn, q1.z, x); x = fmaf(vb.w * rn, q1.w, x);
            rp[ii] = x;
        }
        ((float2*)(ws + WS_PCB + (size_t)e * 512))[tid] = res;
    }
}

// ============ main fused kernel (R8 structure + nt stores) ===================
// grid 2048 x 128 threads (2 waves). Block = 32 tokens: b = blk>>7,
// tb = (blk&127)*32. ph1: 4-way K-split in_proj (partial p = wv*2 + (l>>5),
// rows [p*128,+128), lane&31 = token). ph2: lanes 0-31 finalize z_e.
// ph3: wave wv scans entries [wv*512,+512) as 8/lane (regs), butterfly per
// token. ph4: lanes 0-31 merge waves + loss. ph5: pcb-gather out with
// NON-TEMPORAL stores (write-once data; keep z/pcb in L2/L3).
__global__ __launch_bounds__(128, 4) void vq_main(const float* __restrict__ z,
                                                  const float* __restrict__ b_in,
                                                  const float* __restrict__ ws,
                                                  float* __restrict__ d_out,
                                                  float* __restrict__ bpart) {
    __shared__ float part[4 * 32 * 9];   // 4.6 KB, stride 9
    __shared__ float enorm[32 * 12];     // 1.5 KB: e[8], a, nrm2, zen, pad
    __shared__ float cand_d[64];
    __shared__ int   cand_i[64];
    __shared__ int   idxl[32];

    int tid = threadIdx.x;
    int wv = tid >> 6;
    int l  = tid & 63;
    int half = l >> 5, lt = l & 31;
    int blk = blockIdx.x;
    int b = blk >> 7;
    int tb = (blk & 127) << 5;

    // ---- ph1: in_proj partial (w from global L1, uniform-addr float4) ----
    {
        float acc[8];
#pragma unroll
        for (int j = 0; j < 8; ++j) acc[j] = 0.f;
        const float* zp = z + (size_t)b * D_ * T_ + (size_t)(wv * 256 + half * 128) * T_ + tb + lt;
        const float4* wp = ((const float4*)(ws + WS_WIN_T)) + (wv * 256 + half * 128) * 2;
#pragma unroll 16
        for (int i = 0; i < 128; ++i) {
            float v = zp[(size_t)i * T_];
            float4 wa = wp[i * 2];
            float4 wb = wp[i * 2 + 1];
            acc[0] = fmaf(wa.x, v, acc[0]); acc[1] = fmaf(wa.y, v, acc[1]);
            acc[2] = fmaf(wa.z, v, acc[2]); acc[3] = fmaf(wa.w, v, acc[3]);
            acc[4] = fmaf(wb.x, v, acc[4]); acc[5] = fmaf(wb.y, v, acc[5]);
            acc[6] = fmaf(wb.z, v, acc[6]); acc[7] = fmaf(wb.w, v, acc[7]);
        }
        // slot (p*32 + lt) == (wv*64 + l): conflict-free stride-9 writes
        float* pp = &part[(wv * 64 + l) * 9];
#pragma unroll
        for (int j = 0; j < 8; ++j) pp[j] = acc[j];
    }
    __syncthreads();

    // ---- ph2: lanes 0-31 finalize z_e (bias + 4 partials ascending) ----
    if (tid < 32) {
        float ze[8];
#pragma unroll
        for (int j = 0; j < 8; ++j)
            ze[j] = b_in[j] + part[tid * 9 + j] + part[(32 + tid) * 9 + j]
                  + part[(64 + tid) * 9 + j] + part[(96 + tid) * 9 + j];
        float nrm2 = ze[0] * ze[0] + ze[1] * ze[1] + ze[2] * ze[2] + ze[3] * ze[3]
                   + ze[4] * ze[4] + ze[5] * ze[5] + ze[6] * ze[6] + ze[7] * ze[7];
        float zen = fmaxf(sqrtf(nrm2), 1e-12f);
        float r = 1.0f / zen;
        float e0 = ze[0] * r, e1 = ze[1] * r, e2 = ze[2] * r, e3 = ze[3] * r;
        float e4 = ze[4] * r, e5 = ze[5] * r, e6 = ze[6] * r, e7 = ze[7] * r;
        float a = e0 * e0 + e1 * e1 + e2 * e2 + e3 * e3
                + e4 * e4 + e5 * e5 + e6 * e6 + e7 * e7;
        float* ep = &enorm[tid * 12];
        ep[0] = e0; ep[1] = e1; ep[2] = e2; ep[3] = e3;
        ep[4] = e4; ep[5] = e5; ep[6] = e6; ep[7] = e7;
        ep[8] = a; ep[9] = nrm2; ep[10] = zen; ep[11] = 0.f;
    }

    // ---- load 8 neg-codebook entries/lane: e = wv*512 + k*64 + l ----
    float nc[8][8]; float c2[8];
    int ebase = wv * 512;
#pragma unroll
    for (int k = 0; k < 8; ++k) {
        int e = ebase + k * 64 + l;
        const float4* p = (const float4*)(ws + WS_NCB + (size_t)e * 8);
        float4 p0 = p[0], p1 = p[1];
        nc[k][0] = p0.x; nc[k][1] = p0.y; nc[k][2] = p0.z; nc[k][3] = p0.w;
        nc[k][4] = p1.x; nc[k][5] = p1.y; nc[k][6] = p1.z; nc[k][7] = p1.w;
        c2[k] = ws[WS_QT + (size_t)e * 4 + 2];
    }
    __syncthreads();

    // ---- ph3: score = cc/2 - dot (argmin-equivalent); butterfly lex-min ----
    for (int s = 0; s < 32; ++s) {
        float4 E0 = ((float4*)enorm)[s * 3 + 0];
        float4 E1 = ((float4*)enorm)[s * 3 + 1];
        float sb = 3.4e38f; int bi = 0x7fffffff;
#pragma unroll
        for (int k = 0; k < 8; ++k) {
            float sc = fmaf(nc[k][0], E0.x, c2[k]);
            sc = fmaf(nc[k][1], E0.y, sc);
            sc = fmaf(nc[k][2], E0.z, sc);
            sc = fmaf(nc[k][3], E0.w, sc);
            sc = fmaf(nc[k][4], E1.x, sc);
            sc = fmaf(nc[k][5], E1.y, sc);
            sc = fmaf(nc[k][6], E1.z, sc);
            sc = fmaf(nc[k][7], E1.w, sc);
            int e = ebase + k * 64 + l;
            if (sc < sb) { sb = sc; bi = e; }   // strict < -> first-min
        }
#pragma unroll
        for (int off = 1; off < 64; off <<= 1) {
            float ov = __shfl_xor(sb, off, 64);
            int   oi = __shfl_xor(bi, off, 64);
            if (ov < sb || (ov == sb && oi < bi)) { sb = ov; bi = oi; }
        }
        if (l == 0) { cand_d[wv * 32 + s] = sb; cand_i[wv * 32 + s] = bi; }
    }
    __syncthreads();

    // ---- ph4: lanes 0-31 merge the two waves + loss, one parallel pass ----
    if (tid < 32) {
        float d0 = cand_d[tid];       int i0 = cand_i[tid];
        float d1 = cand_d[32 + tid];  int i1 = cand_i[32 + tid];
        if (d1 < d0) { d0 = d1; i0 = i1; }   // ranges disjoint; wave0 wins ties
        idxl[tid] = i0;
        int tok = blk * 32 + tid;
        d_out[OUT_OFF_IDX + tok] = (float)i0;
        float nrm2 = enorm[tid * 12 + 9], zen = enorm[tid * 12 + 10];
        float4 qt = ((const float4*)(ws + WS_QT))[i0];   // {qn, sw, cc2, 0}
        float dot = qt.z - d0;
        float lv = nrm2 - 2.0f * dot * zen * qt.x + qt.y;
#pragma unroll
        for (int off = 1; off < 32; off <<= 1) lv += __shfl_xor(lv, off, 64);
        if (tid == 0) bpart[blk] = lv;
    }
    __syncthreads();

    // ---- ph5: pcb-gather out, NON-TEMPORAL stores ----
    {
        int tk = tid & 31, q = tid >> 5;
        int idx = idxl[tk];
        const float4* pr = (const float4*)(ws + WS_PCB + (size_t)idx * 512 + q * 128);
        float* op = d_out + (size_t)b * D_ * T_ + (size_t)(q * 128) * T_ + tb + tk;
#pragma unroll 8
        for (int k = 0; k < 32; ++k) {
            float4 v = pr[k];
            __builtin_nontemporal_store(v.x, op + (size_t)(k * 4 + 0) * T_);
            __builtin_nontemporal_store(v.y, op + (size_t)(k * 4 + 1) * T_);
            __builtin_nontemporal_store(v.z, op + (size_t)(k * 4 + 2) * T_);
            __builtin_nontemporal_store(v.w, op + (size_t)(k * 4 + 3) * T_);
        }
    }
}

// ============ finalize: per-batch loss reduction =============================
__global__ __launch_bounds__(64) void vq_finalize(const float* __restrict__ bpart,
                                                  float* __restrict__ d_out) {
    int tid = threadIdx.x;
    if (tid < B_) {
        float s = 0.f;
        for (int k = 0; k < 128; ++k) s += bpart[tid * 128 + k];
        float m = s * (1.0f / (CD_ * T_));
        d_out[OUT_OFF_LOSS + tid] = m;
        d_out[OUT_OFF_LOSS + 16 + tid] = m;
    }
}

// ---------------- launch -----------------------------------------------------
extern "C" void kernel_launch(void* const* d_in, const int* in_sizes, int n_in,
                              void* d_out, int out_size, void* d_ws, size_t ws_size,
                              hipStream_t stream) {
    (void)in_sizes; (void)n_in; (void)out_size; (void)ws_size;
    const float* z        = (const float*)d_in[0];
    const float* v_in     = (const float*)d_in[1];
    const float* g_in     = (const float*)d_in[2];
    const float* b_in     = (const float*)d_in[3];
    const float* v_out    = (const float*)d_in[4];
    const float* g_out    = (const float*)d_in[5];
    const float* b_out    = (const float*)d_in[6];
    const float* codebook = (const float*)d_in[7];
    float* ws  = (float*)d_ws;
    float* out = (float*)d_out;

    hipLaunchKernelGGL(k0_prep, dim3(5 + CBN_), dim3(256), 0, stream,
                       v_in, g_in, v_out, g_out, b_out, codebook, ws);
    hipLaunchKernelGGL(vq_main, dim3(NTOK_ / 32), dim3(128), 0, stream,
                       z, b_in, ws, out, ws + WS_BPART);
    hipLaunchKernelGGL(vq_finalize, dim3(1), dim3(64), 0, stream,
                       ws + WS_BPART, out);
}